// Round 1
// 1181.810 us; speedup vs baseline: 1.0772x; 1.0772x over previous
//
#include <hip/hip_runtime.h>
#include <math.h>

#define BB 2
#define LL 2048
#define MM 16
#define KNN 32

// output element offsets (f32 elements)
#define OFF_V    0
#define OFF_E    8388608
#define OFF_EIDX 25165824
#define OFF_YN   25296896
#define OFF_YE   33685504
#define OFF_YM   167903232
// total 167968768

// atom ids: 0=N 1=Ca 2=C 3=O 4=Cb ; pair g (A from residue i, B from neighbor j)
__device__ const int PAIR_A[24] = {0,2,3,4,1,1,1,1,0,0,0,4,4,3,0,2,3,4,2,3,4,2,3,2};
__device__ const int PAIR_B[24] = {0,2,3,4,0,2,3,4,2,3,4,2,3,2,1,1,1,1,0,0,0,4,4,3};

// ---- parallel LayerNorm stats: R rows of 128 cols in o[.][129], 256 threads ----
template<int R>
__device__ inline void ln_stats(const float (*o)[129], float (*stat)[2], int t)
{
    constexpr int G = 256 / R;   // threads per row (divides 64 for R>=4)
    constexpr int C = 128 / G;   // cols per thread
    const int k = t / G, sub = t % G;
    const float* orow = o[k];
    float s = 0.0f;
    #pragma unroll
    for (int c = 0; c < C; ++c) s += orow[c*G + sub];
    #pragma unroll
    for (int off = G/2; off > 0; off >>= 1) s += __shfl_xor(s, off, 64);
    const float mu = s * 0.0078125f;
    float v = 0.0f;
    #pragma unroll
    for (int c = 0; c < C; ++c) { float d = orow[c*G + sub] - mu; v = fmaf(d, d, v); }
    #pragma unroll
    for (int off = G/2; off > 0; off >>= 1) v += __shfl_xor(v, off, 64);
    if (sub == 0) {
        stat[k][0] = mu;
        stat[k][1] = rsqrtf(v * 0.0078125f + 1e-5f);
    }
}

// ---------------- prep: transpose W_edge/W_down, compute Cb, pack Ca+mask ----------------
__global__ __launch_bounds__(256) void prep_kernel(
    const float* __restrict__ Wedge, const float* __restrict__ Wdown,
    const float* __restrict__ X, const float* __restrict__ mask,
    float* __restrict__ WtE, float* __restrict__ WtD, float* __restrict__ Cb,
    float4* __restrict__ CaM)
{
    int idx = blockIdx.x * 256 + threadIdx.x;
    if (idx < 53248) {                       // WtE[f][c] = W_edge[c][f], 416x128
        int f = idx >> 7, c = idx & 127;
        WtE[idx] = Wedge[c * 416 + f];
    } else if (idx < 53248 + 18944) {        // WtD[f][c] = W_down[c][f], 148x128
        int k = idx - 53248;
        int f = k >> 7, c = k & 127;
        WtD[k] = Wdown[c * 148 + f];
    } else if (idx < 53248 + 18944 + BB * LL) {
        int r = idx - 53248 - 18944;         // residue index b*L+l
        float Nx = X[r*12+0], Ny = X[r*12+1], Nz = X[r*12+2];
        float Ax = X[r*12+3], Ay = X[r*12+4], Az = X[r*12+5];  // Ca
        float Cx = X[r*12+6], Cy = X[r*12+7], Cz = X[r*12+8];
        float bx = Ax - Nx, by = Ay - Ny, bz = Az - Nz;
        float cx = Cx - Ax, cy = Cy - Ay, cz = Cz - Az;
        float ax = by * cz - bz * cy;
        float ay = bz * cx - bx * cz;
        float az = bx * cy - by * cx;
        Cb[r*3+0] = -0.58273431f*ax + 0.56802827f*bx - 0.54067466f*cx + Ax;
        Cb[r*3+1] = -0.58273431f*ay + 0.56802827f*by - 0.54067466f*cy + Ay;
        Cb[r*3+2] = -0.58273431f*az + 0.56802827f*bz - 0.54067466f*cz + Az;
    } else if (idx < 53248 + 18944 + 2 * BB * LL) {
        int r = idx - 53248 - 18944 - BB * LL;
        float4 v;
        v.x = X[r*12+3]; v.y = X[r*12+4]; v.z = X[r*12+5]; v.w = mask[r];
        CaM[r] = v;
    }
}

// ---------------- kNN: register-resident selection, shuffle argmin ----------------
// key = (f32 bits of D_adj << 32) | j  -> lexicographic min == (min dist, min idx),
// exactly matching jax.lax.top_k(-D_adj) ordering with index tie-break.
__global__ __launch_bounds__(256) void knn_kernel(
    const float4* __restrict__ CaM,
    int* __restrict__ eidx, float* __restrict__ dn, float* __restrict__ out)
{
    const int row = blockIdx.x;          // b*L + i
    const int t = threadIdx.x;
    const int b = row >> 11;             // L = 2048
    const int lane = t & 63;
    const int wid = t >> 6;

    __shared__ float wmaxs[4];
    __shared__ unsigned long long wmin[2][4];

    const float4 me = CaM[row];
    float dd[8];
    float m2v[8];
    float lmax = -1e30f;
    #pragma unroll
    for (int s = 0; s < 8; ++s) {
        float4 o4 = CaM[b*LL + s*256 + t];
        float dx = me.x - o4.x, dy = me.y - o4.y, dz = me.z - o4.z;
        float m2 = me.w * o4.w;
        float D = m2 * sqrtf(dx*dx + dy*dy + dz*dz + 1e-6f);
        dd[s] = D;
        m2v[s] = m2;
        lmax = fmaxf(lmax, D);
    }
    #pragma unroll
    for (int off = 32; off > 0; off >>= 1)
        lmax = fmaxf(lmax, __shfl_xor(lmax, off, 64));
    if (lane == 0) wmaxs[wid] = lmax;
    __syncthreads();
    const float Dmax = fmaxf(fmaxf(wmaxs[0], wmaxs[1]), fmaxf(wmaxs[2], wmaxs[3]));

    unsigned long long key[8];
    unsigned long long lmin = ~0ull;
    #pragma unroll
    for (int s = 0; s < 8; ++s) {
        float adj = fmaf(1.0f - m2v[s], Dmax, dd[s]);   // D + (1-m2)*Dmax, D_adj >= 0
        key[s] = ((unsigned long long)__float_as_uint(adj) << 32)
               | (unsigned long long)(unsigned)(s*256 + t);
        lmin = key[s] < lmin ? key[s] : lmin;
    }
    // initial per-wave min (all waves)
    unsigned long long wm = lmin;
    #pragma unroll
    for (int off = 32; off > 0; off >>= 1) {
        unsigned long long o = __shfl_xor(wm, off, 64);
        wm = o < wm ? o : wm;
    }
    if (lane == 0) wmin[0][wid] = wm;
    __syncthreads();

    int p = 0;
    for (int sel = 0; sel < KNN; ++sel) {
        unsigned long long g = wmin[p][0];
        g = wmin[p][1] < g ? wmin[p][1] : g;
        g = wmin[p][2] < g ? wmin[p][2] : g;
        g = wmin[p][3] < g ? wmin[p][3] : g;
        if (t == 0) {
            int j = (int)(g & 0x7ff);
            eidx[row*KNN + sel] = j;
            dn[row*KNN + sel] = __uint_as_float((unsigned)(g >> 32));
            out[OFF_EIDX + row*KNN + sel] = (float)j;
        }
        if (sel == KNN - 1) break;
        // remove winner; only the winner's wave recomputes its wave-min
        const int jwin = (int)(g & 0x7ff);
        const int wwid = (jwin & 255) >> 6;
        if (wid == wwid) {
            #pragma unroll
            for (int s = 0; s < 8; ++s) key[s] = (key[s] == g) ? ~0ull : key[s];
            unsigned long long m = key[0];
            #pragma unroll
            for (int s = 1; s < 8; ++s) m = key[s] < m ? key[s] : m;
            #pragma unroll
            for (int off = 32; off > 0; off >>= 1) {
                unsigned long long o = __shfl_xor(m, off, 64);
                m = o < m ? o : m;
            }
            wm = m;
        }
        if (lane == 0) wmin[p^1][wid] = wm;
        __syncthreads();
        p ^= 1;
    }
}

// ---------------- edges: features + 416->128 linear + LN ----------------
__global__ __launch_bounds__(256) void edge_kernel(
    const float* __restrict__ X, const float* __restrict__ Cb,
    const int* __restrict__ Ridx, const int* __restrict__ chains,
    const float* __restrict__ Wpos, const float* __restrict__ bpos,
    const float* __restrict__ Wt, const float* __restrict__ bedge,
    const float* __restrict__ ge, const float* __restrict__ be,
    const int* __restrict__ eidx, const float* __restrict__ dn,
    float* __restrict__ out)
{
    const int row = blockIdx.x;   // b*L + i
    const int t = threadIdx.x;
    const int b = row >> 11;
    __shared__ __attribute__((aligned(16))) float smem[KNN*420];   // feat, later aliased as o
    float (*feat)[420] = (float(*)[420])smem;
    float (*o)[129] = (float(*)[129])smem;
    __shared__ float jat[KNN][15];
    __shared__ float dd[KNN][25];
    __shared__ float iat[15];
    __shared__ int   jd[KNN];
    __shared__ float stat[KNN][2];

    if (t < 12) iat[t] = X[row*12 + t];
    else if (t < 15) iat[t] = Cb[row*3 + (t-12)];
    if (t < KNN) {
        int j = eidx[row*KNN + t];
        int gj = b*LL + j;
        #pragma unroll
        for (int q = 0; q < 12; ++q) jat[t][q] = X[gj*12 + q];
        jat[t][12] = Cb[gj*3+0];
        jat[t][13] = Cb[gj*3+1];
        jat[t][14] = Cb[gj*3+2];
        int off = Ridx[row] - Ridx[gj];
        int dcl = off + 32;
        dcl = dcl < 0 ? 0 : (dcl > 64 ? 64 : dcl);
        jd[t] = (chains[row] == chains[gj]) ? dcl : 65;
        dd[t][0] = dn[row*KNN + t];
    }
    __syncthreads();
    for (int idx = t; idx < 24*KNN; idx += 256) {
        int k = idx & (KNN-1);
        int gp = idx >> 5;
        int a = PAIR_A[gp], b2 = PAIR_B[gp];
        float dx = iat[a*3+0] - jat[k][b2*3+0];
        float dy = iat[a*3+1] - jat[k][b2*3+1];
        float dz = iat[a*3+2] - jat[k][b2*3+2];
        dd[k][gp+1] = sqrtf(dx*dx + dy*dy + dz*dz + 1e-6f);
    }
    __syncthreads();
    for (int idx = t; idx < KNN*400; idx += 256) {
        int k = idx / 400;
        int f = idx - k*400;
        float d = dd[k][f >> 4];
        int r = f & 15;
        float z = (d - (2.0f + 1.3333333333f*(float)r)) * 0.8f;
        feat[k][16 + f] = expf(-z*z);
    }
    for (int idx = t; idx < KNN*16; idx += 256) {
        int k = idx >> 4, p = idx & 15;
        feat[k][p] = Wpos[p*66 + jd[k]] + bpos[p];
    }
    __syncthreads();
    const int c2 = (t & 63) * 2;
    const int g4 = t >> 6;             // 4 groups x 8 rows
    float acc[8][2];
    #pragma unroll
    for (int r = 0; r < 8; ++r) { acc[r][0] = bedge[c2]; acc[r][1] = bedge[c2+1]; }
    for (int f = 0; f < 416; f += 4) {
        const float2 w0 = *(const float2*)&Wt[(f+0)*128 + c2];
        const float2 w1 = *(const float2*)&Wt[(f+1)*128 + c2];
        const float2 w2 = *(const float2*)&Wt[(f+2)*128 + c2];
        const float2 w3 = *(const float2*)&Wt[(f+3)*128 + c2];
        #pragma unroll
        for (int r = 0; r < 8; ++r) {
            const float4 fv = *(const float4*)&feat[g4*8 + r][f];
            acc[r][0] = fmaf(fv.x, w0.x, acc[r][0]);
            acc[r][0] = fmaf(fv.y, w1.x, acc[r][0]);
            acc[r][0] = fmaf(fv.z, w2.x, acc[r][0]);
            acc[r][0] = fmaf(fv.w, w3.x, acc[r][0]);
            acc[r][1] = fmaf(fv.x, w0.y, acc[r][1]);
            acc[r][1] = fmaf(fv.y, w1.y, acc[r][1]);
            acc[r][1] = fmaf(fv.z, w2.y, acc[r][1]);
            acc[r][1] = fmaf(fv.w, w3.y, acc[r][1]);
        }
    }
    __syncthreads();   // feat no longer needed; alias as o
    #pragma unroll
    for (int r = 0; r < 8; ++r) {
        o[g4*8 + r][c2]   = acc[r][0];
        o[g4*8 + r][c2+1] = acc[r][1];
    }
    __syncthreads();
    ln_stats<KNN>(o, stat, t);
    __syncthreads();
    const size_t base = (size_t)OFF_E + (size_t)row * KNN * 128;
    for (int idx = t; idx < KNN*128; idx += 256) {
        int k = idx >> 7, c = idx & 127;
        out[base + idx] = (o[k][c] - stat[k][0]) * stat[k][1] * ge[c] + be[c];
    }
}

// ---------------- nodes: V (148->128 + LN) and Y_nodes (gather + LN) ----------------
__global__ __launch_bounds__(256) void node_kernel(
    const float* __restrict__ X, const float* __restrict__ CbA,
    const float* __restrict__ Yp, const int* __restrict__ Yt,
    const int* __restrict__ ptab,
    const float* __restrict__ Wtype, const float* __restrict__ btype,
    const float* __restrict__ WtD, const float* __restrict__ bdown,
    const float* __restrict__ gnode, const float* __restrict__ bnnode,
    const float* __restrict__ Wyn, const float* __restrict__ byn,
    const float* __restrict__ gyn, const float* __restrict__ bnyn,
    float* __restrict__ out)
{
    const int row = blockIdx.x;   // b*L + l
    const int t = threadIdx.x;
    __shared__ float atoms[5][3];          // N Ca C O Cb
    __shared__ float evec[3][3];
    __shared__ float Ys[MM][3];
    __shared__ float dst[5][MM];
    __shared__ __attribute__((aligned(16))) float feat[MM][152];
    __shared__ float o[MM][129];
    __shared__ float stat[MM][2];
    __shared__ int tinfo[MM][3];

    if (t < 12) atoms[t/3][t%3] = X[row*12 + t];
    else if (t < 15) atoms[4][t-12] = CbA[row*3 + (t-12)];
    if (t >= 16 && t < 64) { int q = t - 16; Ys[q/3][q%3] = Yp[row*48 + q]; }
    if (t >= 64 && t < 80) {
        int m = t - 64;
        int ty = Yt[row*16 + m];
        tinfo[m][0] = ty;
        tinfo[m][1] = ptab[120 + ty];
        tinfo[m][2] = ptab[240 + ty];
    }
    __syncthreads();
    if (t == 0) {
        float v1x = atoms[0][0]-atoms[1][0], v1y = atoms[0][1]-atoms[1][1], v1z = atoms[0][2]-atoms[1][2];
        float v2x = atoms[2][0]-atoms[1][0], v2y = atoms[2][1]-atoms[1][1], v2z = atoms[2][2]-atoms[1][2];
        float n1 = sqrtf(v1x*v1x + v1y*v1y + v1z*v1z) + 1e-8f;
        float e1x = v1x/n1, e1y = v1y/n1, e1z = v1z/n1;
        float dp = e1x*v2x + e1y*v2y + e1z*v2z;
        float u2x = v2x - e1x*dp, u2y = v2y - e1y*dp, u2z = v2z - e1z*dp;
        float n2 = sqrtf(u2x*u2x + u2y*u2y + u2z*u2z) + 1e-8f;
        float e2x = u2x/n2, e2y = u2y/n2, e2z = u2z/n2;
        evec[0][0] = e1x; evec[0][1] = e1y; evec[0][2] = e1z;
        evec[1][0] = e2x; evec[1][1] = e2y; evec[1][2] = e2z;
        evec[2][0] = e1y*e2z - e1z*e2y;
        evec[2][1] = e1z*e2x - e1x*e2z;
        evec[2][2] = e1x*e2y - e1y*e2x;
    }
    if (t >= 128 && t < 208) {
        int q = t - 128;
        int a = q >> 4, m = q & 15;
        float dx = atoms[a][0]-Ys[m][0];
        float dy = atoms[a][1]-Ys[m][1];
        float dz = atoms[a][2]-Ys[m][2];
        dst[a][m] = sqrtf(dx*dx + dy*dy + dz*dz + 1e-6f);
    }
    __syncthreads();
    for (int idx = t; idx < 5*16*16; idx += 256) {
        int a = idx >> 8, m = (idx >> 4) & 15, r = idx & 15;
        float z = (dst[a][m] - (2.0f + 1.3333333333f*(float)r)) * 0.8f;
        feat[m][a*16 + r] = expf(-z*z);
    }
    for (int idx = t; idx < 1024; idx += 256) {
        int m = idx >> 6, c = idx & 63;
        const float* wr = Wtype + c*147;
        feat[m][80 + c] = wr[tinfo[m][0]] + wr[120 + tinfo[m][1]] + wr[139 + tinfo[m][2]] + btype[c];
    }
    if (t < 16) {
        int m = t;
        float dx = Ys[m][0]-atoms[1][0], dy = Ys[m][1]-atoms[1][1], dz = Ys[m][2]-atoms[1][2];
        float l0 = evec[0][0]*dx + evec[0][1]*dy + evec[0][2]*dz;
        float l1 = evec[1][0]*dx + evec[1][1]*dy + evec[1][2]*dz;
        float l2 = evec[2][0]*dx + evec[2][1]*dy + evec[2][2]*dz;
        float rxy  = sqrtf(l0*l0 + l1*l1 + 1e-8f);
        float rxyz = sqrtf(l0*l0 + l1*l1 + l2*l2) + 1e-8f;
        feat[m][144] = l0 / rxy;
        feat[m][145] = l1 / rxy;
        feat[m][146] = rxy / rxyz;
        feat[m][147] = l2 / rxyz;
    }
    __syncthreads();
    const int c2 = (t & 63) * 2;
    const int g4 = t >> 6;            // 4 groups x 4 rows
    float acc[4][2];
    #pragma unroll
    for (int r = 0; r < 4; ++r) { acc[r][0] = bdown[c2]; acc[r][1] = bdown[c2+1]; }
    for (int f = 0; f < 148; f += 4) {
        const float2 w0 = *(const float2*)&WtD[(f+0)*128 + c2];
        const float2 w1 = *(const float2*)&WtD[(f+1)*128 + c2];
        const float2 w2 = *(const float2*)&WtD[(f+2)*128 + c2];
        const float2 w3 = *(const float2*)&WtD[(f+3)*128 + c2];
        #pragma unroll
        for (int r = 0; r < 4; ++r) {
            const float4 fv = *(const float4*)&feat[g4*4 + r][f];
            acc[r][0] = fmaf(fv.x, w0.x, acc[r][0]);
            acc[r][0] = fmaf(fv.y, w1.x, acc[r][0]);
            acc[r][0] = fmaf(fv.z, w2.x, acc[r][0]);
            acc[r][0] = fmaf(fv.w, w3.x, acc[r][0]);
            acc[r][1] = fmaf(fv.x, w0.y, acc[r][1]);
            acc[r][1] = fmaf(fv.y, w1.y, acc[r][1]);
            acc[r][1] = fmaf(fv.z, w2.y, acc[r][1]);
            acc[r][1] = fmaf(fv.w, w3.y, acc[r][1]);
        }
    }
    #pragma unroll
    for (int r = 0; r < 4; ++r) {
        o[g4*4 + r][c2]   = acc[r][0];
        o[g4*4 + r][c2+1] = acc[r][1];
    }
    __syncthreads();
    ln_stats<MM>(o, stat, t);
    __syncthreads();
    const size_t vbase = (size_t)OFF_V + (size_t)row * 2048;
    for (int idx = t; idx < 2048; idx += 256) {
        int k = idx >> 7, c = idx & 127;
        out[vbase + idx] = (o[k][c] - stat[k][0]) * stat[k][1] * gnode[c] + bnnode[c];
    }
    __syncthreads();   // done reading o; reuse for Y_nodes
    for (int idx = t; idx < 2048; idx += 256) {
        int m = idx >> 7, c = idx & 127;
        const float* wr = Wyn + c*147;
        o[m][c] = wr[tinfo[m][0]] + wr[120 + tinfo[m][1]] + wr[139 + tinfo[m][2]] + byn[c];
    }
    __syncthreads();
    ln_stats<MM>(o, stat, t);
    __syncthreads();
    const size_t ybase = (size_t)OFF_YN + (size_t)row * 2048;
    for (int idx = t; idx < 2048; idx += 256) {
        int k = idx >> 7, c = idx & 127;
        out[ybase + idx] = (o[k][c] - stat[k][0]) * stat[k][1] * gyn[c] + bnyn[c];
    }
}

// ---------------- Y_edges: 16 rbf -> 128 + LN, 64 (m1,m2) rows per block ----------------
__global__ __launch_bounds__(256) void yedge_kernel(
    const float* __restrict__ Yp, const float* __restrict__ Wye,
    const float* __restrict__ bye, const float* __restrict__ gye,
    const float* __restrict__ bnye, float* __restrict__ out)
{
    const int blk = blockIdx.x;
    const int row = blk >> 2;          // b*L + l
    const int r0 = (blk & 3) * 64;
    const int t = threadIdx.x;
    __shared__ float Ys[MM][3];
    __shared__ __attribute__((aligned(16))) float Wt[16][128];
    __shared__ __attribute__((aligned(16))) float feat[64][20];
    __shared__ float o[64][129];
    __shared__ float stat[64][2];

    if (t < 48) Ys[t/3][t%3] = Yp[row*48 + t];
    for (int idx = t; idx < 2048; idx += 256) {
        int c = idx & 127, f = idx >> 7;
        Wt[f][c] = Wye[c*16 + f];
    }
    __syncthreads();
    for (int idx = t; idx < 64*16; idx += 256) {
        int r = idx >> 4, rr = idx & 15;
        int gr = r0 + r;
        int m1 = gr >> 4, m2 = gr & 15;
        float dx = Ys[m1][0]-Ys[m2][0];
        float dy = Ys[m1][1]-Ys[m2][1];
        float dz = Ys[m1][2]-Ys[m2][2];
        float d = sqrtf(dx*dx + dy*dy + dz*dz + 1e-6f);
        float z = (d - (2.0f + 1.3333333333f*(float)rr)) * 0.8f;
        feat[r][rr] = expf(-z*z);
    }
    __syncthreads();
    const int c2 = (t & 63) * 2;
    const int g4 = t >> 6;             // 4 groups x 16 rows
    float acc[16][2];
    #pragma unroll
    for (int r = 0; r < 16; ++r) { acc[r][0] = bye[c2]; acc[r][1] = bye[c2+1]; }
    #pragma unroll
    for (int f = 0; f < 16; f += 4) {
        const float2 w0 = *(const float2*)&Wt[f+0][c2];
        const float2 w1 = *(const float2*)&Wt[f+1][c2];
        const float2 w2 = *(const float2*)&Wt[f+2][c2];
        const float2 w3 = *(const float2*)&Wt[f+3][c2];
        #pragma unroll
        for (int r = 0; r < 16; ++r) {
            const float4 fv = *(const float4*)&feat[g4*16 + r][f];
            acc[r][0] = fmaf(fv.x, w0.x, acc[r][0]);
            acc[r][0] = fmaf(fv.y, w1.x, acc[r][0]);
            acc[r][0] = fmaf(fv.z, w2.x, acc[r][0]);
            acc[r][0] = fmaf(fv.w, w3.x, acc[r][0]);
            acc[r][1] = fmaf(fv.x, w0.y, acc[r][1]);
            acc[r][1] = fmaf(fv.y, w1.y, acc[r][1]);
            acc[r][1] = fmaf(fv.z, w2.y, acc[r][1]);
            acc[r][1] = fmaf(fv.w, w3.y, acc[r][1]);
        }
    }
    #pragma unroll
    for (int r = 0; r < 16; ++r) {
        o[g4*16 + r][c2]   = acc[r][0];
        o[g4*16 + r][c2+1] = acc[r][1];
    }
    __syncthreads();
    ln_stats<64>(o, stat, t);
    __syncthreads();
    const size_t base = (size_t)OFF_YE + ((size_t)row * 256 + r0) * 128;
    for (int idx = t; idx < 64*128; idx += 256) {
        int k = idx >> 7, c = idx & 127;
        out[base + idx] = (o[k][c] - stat[k][0]) * stat[k][1] * gye[c] + bnye[c];
    }
}

extern "C" void kernel_launch(void* const* d_in, const int* in_sizes, int n_in,
                              void* d_out, int out_size, void* d_ws, size_t ws_size,
                              hipStream_t stream) {
    (void)in_sizes; (void)n_in; (void)out_size; (void)ws_size;
    const float* X      = (const float*)d_in[0];
    const float* Y      = (const float*)d_in[1];
    const float* Y_m    = (const float*)d_in[2];
    const float* mask   = (const float*)d_in[3];
    const float* W_pos  = (const float*)d_in[4];
    const float* b_pos  = (const float*)d_in[5];
    const float* W_edge = (const float*)d_in[6];
    const float* b_edge = (const float*)d_in[7];
    const float* g_edge = (const float*)d_in[8];
    const float* be_edge= (const float*)d_in[9];
    const float* W_down = (const float*)d_in[10];
    const float* b_down = (const float*)d_in[11];
    const float* g_node = (const float*)d_in[12];
    const float* bn_node= (const float*)d_in[13];
    const float* W_type = (const float*)d_in[14];
    const float* b_type = (const float*)d_in[15];
    const float* W_yn   = (const float*)d_in[16];
    const float* b_yn   = (const float*)d_in[17];
    const float* g_yn   = (const float*)d_in[18];
    const float* bn_yn  = (const float*)d_in[19];
    const float* W_ye   = (const float*)d_in[20];
    const float* b_ye   = (const float*)d_in[21];
    const float* g_ye   = (const float*)d_in[22];
    const float* bn_ye  = (const float*)d_in[23];
    const int* Y_t      = (const int*)d_in[24];
    const int* R_idx    = (const int*)d_in[25];
    const int* chains   = (const int*)d_in[26];
    const int* ptab     = (const int*)d_in[27];

    float* out = (float*)d_out;
    float* ws  = (float*)d_ws;
    float* WtE = ws;                       // 53248
    float* WtD = ws + 53248;               // 18944
    float* Cb  = ws + 72192;               // 12288
    int*   eidx = (int*)(ws + 84480);      // 131072
    float* dn  = ws + 215552;              // 131072

    // Ca+mask packed float4, stashed in the Y_edges output region (written only
    // by yedge_kernel, which runs after knn_kernel has consumed this).
    float* CaM = out + OFF_YE;             // 16384 floats, 16B-aligned

    prep_kernel<<<314, 256, 0, stream>>>(W_edge, W_down, X, mask, WtE, WtD, Cb,
                                         (float4*)CaM);
    knn_kernel<<<BB*LL, 256, 0, stream>>>((const float4*)CaM, eidx, dn, out);
    edge_kernel<<<BB*LL, 256, 0, stream>>>(X, Cb, R_idx, chains, W_pos, b_pos,
                                           WtE, b_edge, g_edge, be_edge, eidx, dn, out);
    node_kernel<<<BB*LL, 256, 0, stream>>>(X, Cb, Y, Y_t, ptab, W_type, b_type,
                                           WtD, b_down, g_node, bn_node,
                                           W_yn, b_yn, g_yn, bn_yn, out);
    yedge_kernel<<<BB*LL*4, 256, 0, stream>>>(Y, W_ye, b_ye, g_ye, bn_ye, out);
    hipMemcpyAsync(out + OFF_YM, Y_m, (size_t)BB*LL*MM*sizeof(float),
                   hipMemcpyDeviceToDevice, stream);
}